// Round 1
// baseline (185.015 us; speedup 1.0000x reference)
//
#include <hip/hip_runtime.h>

#define H    256
#define W    256
#define WH   129            // W/2 + 1
#define VLEN 182            // max radial bin + 1
#define NIMG 64             // 32 pred + 32 target

__device__ __forceinline__ int bitrev8(int x) {
    return (int)(__brev((unsigned)x) >> 24);
}

// 256-point complex FFT in shared memory, DIT radix-2.
// 128 threads, sh[256] already loaded in bit-reversed order, twid[m] = e^{-2*pi*i*m/256}.
__device__ __forceinline__ void fft256(float2* sh, const float2* twid, int t) {
    #pragma unroll
    for (int lg = 1; lg <= 8; ++lg) {
        const int half = 1 << (lg - 1);
        const int pos  = t & (half - 1);
        const int i0   = ((t >> (lg - 1)) << lg) + pos;
        const int i1   = i0 + half;
        const float2 w = twid[pos << (8 - lg)];
        const float2 u = sh[i0];
        const float2 v = sh[i1];
        const float2 tv = make_float2(v.x * w.x - v.y * w.y,
                                      v.x * w.y + v.y * w.x);
        sh[i0] = make_float2(u.x + tv.x, u.y + tv.y);
        sh[i1] = make_float2(u.x - tv.x, u.y - tv.y);
        __syncthreads();
    }
}

__device__ __forceinline__ void init_twiddles(float2* twid, int t) {
    // t in [0,128)
    float s, c;
    sincosf(-6.283185307179586476925287e0f * (float)t / 256.0f, &s, &c);
    twid[t] = make_float2(c, s);
}

// One block of 128 threads per image row: luma + real FFT along W (keep 129 bins).
__global__ __launch_bounds__(128)
void gray_rowfft(const float* __restrict__ pred, const float* __restrict__ targ,
                 float2* __restrict__ spec /* [NIMG][H][WH] */) {
    __shared__ float2 sh[256];
    __shared__ float2 twid[128];
    const int t   = threadIdx.x;
    const int row = blockIdx.x;        // 0 .. NIMG*H-1
    const int img = row >> 8;
    const int i   = row & 255;
    const float* src  = (img < 32) ? pred : targ;
    const float* base = src + (size_t)(img & 31) * (3 * H * W) + (size_t)i * W;

    init_twiddles(twid, t);
    for (int n = t; n < 256; n += 128) {
        const float g = 0.299f * base[n]
                      + 0.587f * base[H * W + n]
                      + 0.114f * base[2 * H * W + n];
        sh[bitrev8(n)] = make_float2(g, 0.0f);
    }
    __syncthreads();

    fft256(sh, twid, t);

    float2* dst = spec + (size_t)img * (H * WH) + (size_t)i * WH;
    for (int k = t; k < WH; k += 128) dst[k] = sh[k];
}

// One block of 128 threads per (image, column): complex FFT along H, in place.
__global__ __launch_bounds__(128)
void colfft(float2* __restrict__ spec) {
    __shared__ float2 sh[256];
    __shared__ float2 twid[128];
    const int t   = threadIdx.x;
    const int idx = blockIdx.x;        // 0 .. NIMG*WH-1
    const int img = idx / WH;
    const int j   = idx - img * WH;
    float2* base = spec + (size_t)img * (H * WH) + j;

    init_twiddles(twid, t);
    for (int n = t; n < 256; n += 128)
        sh[bitrev8(n)] = base[(size_t)n * WH];
    __syncthreads();

    fft256(sh, twid, t);

    for (int n = t; n < 256; n += 128)
        base[(size_t)n * WH] = sh[n];
}

// One block of 256 threads per image: log-power, radial segment mean, min/max normalize.
__global__ __launch_bounds__(256)
void profile_kernel(const float2* __restrict__ spec, float* __restrict__ prof) {
    __shared__ float ssum[VLEN];
    __shared__ float scnt[VLEN];
    __shared__ float red[256];
    const int t   = threadIdx.x;
    const int img = blockIdx.x;

    for (int v = t; v < VLEN; v += 256) { ssum[v] = 0.0f; scnt[v] = 0.0f; }
    __syncthreads();

    const float2* base = spec + (size_t)img * (H * WH);
    for (int e = t; e < H * WH; e += 256) {
        const int k  = e / WH;
        const int j  = e - k * WH;
        const int di = (k < 128) ? k : k - 256;
        const int s2 = di * di + j * j;
        int r = (int)sqrtf((float)s2);
        while ((r + 1) * (r + 1) <= s2) ++r;   // exact floor(sqrt) fixup
        while (r * r > s2) --r;
        const float2 F = base[e];
        const float mag = 20.0f * logf(F.x * F.x + F.y * F.y + 1e-8f);
        atomicAdd(&ssum[r], mag);
        atomicAdd(&scnt[r], 1.0f);
    }
    __syncthreads();

    for (int v = t; v < VLEN; v += 256) ssum[v] = ssum[v] / scnt[v];
    __syncthreads();

    // block-min of per-bin means
    float lmin = 3.4e38f;
    for (int v = t; v < VLEN; v += 256) lmin = fminf(lmin, ssum[v]);
    red[t] = lmin; __syncthreads();
    for (int off = 128; off > 0; off >>= 1) {
        if (t < off) red[t] = fminf(red[t], red[t + off]);
        __syncthreads();
    }
    const float mn = red[0];
    __syncthreads();

    // block-max of shifted means
    float lmax = -3.4e38f;
    for (int v = t; v < VLEN; v += 256) lmax = fmaxf(lmax, ssum[v] - mn);
    red[t] = lmax; __syncthreads();
    for (int off = 128; off > 0; off >>= 1) {
        if (t < off) red[t] = fmaxf(red[t], red[t + off]);
        __syncthreads();
    }
    const float mx = red[0];

    for (int v = t; v < VLEN; v += 256)
        prof[(size_t)img * VLEN + v] = (ssum[v] - mn) / mx;
}

// Single block: MSE over 32 x VLEN pred/target profile pairs.
__global__ __launch_bounds__(256)
void mse_kernel(const float* __restrict__ prof, float* __restrict__ out) {
    __shared__ float red[256];
    const int t = threadIdx.x;
    const int n = 32 * VLEN;
    float acc = 0.0f;
    for (int e = t; e < n; e += 256) {
        const float d = prof[e] - prof[e + n];
        acc += d * d;
    }
    red[t] = acc; __syncthreads();
    for (int off = 128; off > 0; off >>= 1) {
        if (t < off) red[t] += red[t + off];
        __syncthreads();
    }
    if (t == 0) out[0] = red[0] / (float)n;
}

extern "C" void kernel_launch(void* const* d_in, const int* in_sizes, int n_in,
                              void* d_out, int out_size, void* d_ws, size_t ws_size,
                              hipStream_t stream) {
    const float* pred = (const float*)d_in[0];
    const float* targ = (const float*)d_in[1];
    float* out = (float*)d_out;

    float2* spec = (float2*)d_ws;                                   // NIMG*H*WH complex
    float*  prof = (float*)((char*)d_ws +
                            (size_t)NIMG * H * WH * sizeof(float2)); // NIMG*VLEN floats

    gray_rowfft<<<NIMG * H, 128, 0, stream>>>(pred, targ, spec);
    colfft<<<NIMG * WH, 128, 0, stream>>>(spec);
    profile_kernel<<<NIMG, 256, 0, stream>>>(spec, prof);
    mse_kernel<<<1, 256, 0, stream>>>(prof, out);
}

// Round 2
// 100.351 us; speedup vs baseline: 1.8437x; 1.8437x over previous
//
#include <hip/hip_runtime.h>

#define H    256
#define W    256
#define WH   129            // W/2 + 1
#define VLEN 182            // max radial bin + 1
#define NIMG 64             // 32 pred + 32 target

__device__ __forceinline__ int bitrev8(int x) {
    return (int)(__brev((unsigned)x) >> 24);
}

__device__ __forceinline__ int isqrt_exact(int s2) {
    int r = (int)sqrtf((float)s2);
    while ((r + 1) * (r + 1) <= s2) ++r;
    while (r * r > s2) --r;
    return r;
}

// 256-point complex FFT in shared memory, DIT radix-2.
// 128 threads, sh[256] already loaded in bit-reversed order, twid[m] = e^{-2*pi*i*m/256}.
__device__ __forceinline__ void fft256(float2* sh, const float2* twid, int t) {
    #pragma unroll
    for (int lg = 1; lg <= 8; ++lg) {
        const int half = 1 << (lg - 1);
        const int pos  = t & (half - 1);
        const int i0   = ((t >> (lg - 1)) << lg) + pos;
        const int i1   = i0 + half;
        const float2 w = twid[pos << (8 - lg)];
        const float2 u = sh[i0];
        const float2 v = sh[i1];
        const float2 tv = make_float2(v.x * w.x - v.y * w.y,
                                      v.x * w.y + v.y * w.x);
        sh[i0] = make_float2(u.x + tv.x, u.y + tv.y);
        sh[i1] = make_float2(u.x - tv.x, u.y - tv.y);
        __syncthreads();
    }
}

__device__ __forceinline__ void init_twiddles(float2* twid, int t) {
    float s, c;
    sincosf(-6.283185307179586476925287e0f * (float)t / 256.0f, &s, &c);
    twid[t] = make_float2(c, s);
}

// One block of 128 threads per image row: luma + real FFT along W (keep 129 bins).
__global__ __launch_bounds__(128)
void gray_rowfft(const float* __restrict__ pred, const float* __restrict__ targ,
                 float2* __restrict__ spec /* [NIMG][H][WH] */) {
    __shared__ float2 sh[256];
    __shared__ float2 twid[128];
    const int t   = threadIdx.x;
    const int row = blockIdx.x;        // 0 .. NIMG*H-1
    const int img = row >> 8;
    const int i   = row & 255;
    const float* src  = (img < 32) ? pred : targ;
    const float* base = src + (size_t)(img & 31) * (3 * H * W) + (size_t)i * W;

    init_twiddles(twid, t);
    for (int n = t; n < 256; n += 128) {
        const float g = 0.299f * base[n]
                      + 0.587f * base[H * W + n]
                      + 0.114f * base[2 * H * W + n];
        sh[bitrev8(n)] = make_float2(g, 0.0f);
    }
    __syncthreads();

    fft256(sh, twid, t);

    float2* dst = spec + (size_t)img * (H * WH) + (size_t)i * WH;
    for (int k = t; k < WH; k += 128) dst[k] = sh[k];
}

// One block of 128 threads per (image, column): complex FFT along H, fused
// log-power + radial binning. Flushes per-block LDS bins to global sums.
__global__ __launch_bounds__(128)
void colfft_profile(const float2* __restrict__ spec,
                    float* __restrict__ gsum /* [NIMG][VLEN], pre-zeroed */) {
    __shared__ float2 sh[256];
    __shared__ float2 twid[128];
    __shared__ float bins[VLEN];
    const int t   = threadIdx.x;
    const int idx = blockIdx.x;        // 0 .. NIMG*WH-1
    const int img = idx / WH;
    const int j   = idx - img * WH;
    const float2* base = spec + (size_t)img * (H * WH) + j;

    init_twiddles(twid, t);
    for (int v = t; v < VLEN; v += 128) bins[v] = 0.0f;
    for (int n = t; n < 256; n += 128)
        sh[bitrev8(n)] = base[(size_t)n * WH];
    __syncthreads();

    fft256(sh, twid, t);

    const int j2 = j * j;
    for (int n = t; n < 256; n += 128) {
        const int di = (n < 128) ? n : n - 256;
        const int r  = isqrt_exact(di * di + j2);
        const float2 F = sh[n];
        const float mag = 20.0f * logf(F.x * F.x + F.y * F.y + 1e-8f);
        atomicAdd(&bins[r], mag);
    }
    __syncthreads();

    // only bins in [j, floor(sqrt(128^2+j^2))] are touched by this column
    const int rmax = isqrt_exact(128 * 128 + j2);
    float* gs = gsum + (size_t)img * VLEN;
    for (int v = j + t; v <= rmax; v += 128)
        atomicAdd(&gs[v], bins[v]);
}

// One block of 256 threads per image: per-bin mean, min/max normalize.
// Bin counts are static; recompute them in-register (no loads).
__global__ __launch_bounds__(256)
void normalize_kernel(const float* __restrict__ gsum, float* __restrict__ prof) {
    __shared__ float ssum[VLEN];
    __shared__ int   scnt[VLEN];
    __shared__ float red[256];
    const int t   = threadIdx.x;
    const int img = blockIdx.x;

    for (int v = t; v < VLEN; v += 256) scnt[v] = 0;
    __syncthreads();

    for (int e = t; e < H * WH; e += 256) {
        const int k  = e / WH;
        const int j  = e - k * WH;
        const int di = (k < 128) ? k : k - 256;
        const int r  = isqrt_exact(di * di + j * j);
        atomicAdd(&scnt[r], 1);
    }
    __syncthreads();

    for (int v = t; v < VLEN; v += 256)
        ssum[v] = gsum[(size_t)img * VLEN + v] / (float)scnt[v];
    __syncthreads();

    float lmin = 3.4e38f;
    for (int v = t; v < VLEN; v += 256) lmin = fminf(lmin, ssum[v]);
    red[t] = lmin; __syncthreads();
    for (int off = 128; off > 0; off >>= 1) {
        if (t < off) red[t] = fminf(red[t], red[t + off]);
        __syncthreads();
    }
    const float mn = red[0];
    __syncthreads();

    float lmax = -3.4e38f;
    for (int v = t; v < VLEN; v += 256) lmax = fmaxf(lmax, ssum[v] - mn);
    red[t] = lmax; __syncthreads();
    for (int off = 128; off > 0; off >>= 1) {
        if (t < off) red[t] = fmaxf(red[t], red[t + off]);
        __syncthreads();
    }
    const float mx = red[0];

    for (int v = t; v < VLEN; v += 256)
        prof[(size_t)img * VLEN + v] = (ssum[v] - mn) / mx;
}

// Single block: MSE over 32 x VLEN pred/target profile pairs.
__global__ __launch_bounds__(256)
void mse_kernel(const float* __restrict__ prof, float* __restrict__ out) {
    __shared__ float red[256];
    const int t = threadIdx.x;
    const int n = 32 * VLEN;
    float acc = 0.0f;
    for (int e = t; e < n; e += 256) {
        const float d = prof[e] - prof[e + n];
        acc += d * d;
    }
    red[t] = acc; __syncthreads();
    for (int off = 128; off > 0; off >>= 1) {
        if (t < off) red[t] += red[t + off];
        __syncthreads();
    }
    if (t == 0) out[0] = red[0] / (float)n;
}

extern "C" void kernel_launch(void* const* d_in, const int* in_sizes, int n_in,
                              void* d_out, int out_size, void* d_ws, size_t ws_size,
                              hipStream_t stream) {
    const float* pred = (const float*)d_in[0];
    const float* targ = (const float*)d_in[1];
    float* out = (float*)d_out;

    char* ws = (char*)d_ws;
    float2* spec = (float2*)ws;                                  // NIMG*H*WH complex
    ws += (size_t)NIMG * H * WH * sizeof(float2);
    float* gsum = (float*)ws;                                    // NIMG*VLEN floats
    ws += (size_t)NIMG * VLEN * sizeof(float);
    float* prof = (float*)ws;                                    // NIMG*VLEN floats

    hipMemsetAsync(gsum, 0, (size_t)NIMG * VLEN * sizeof(float), stream);

    gray_rowfft<<<NIMG * H, 128, 0, stream>>>(pred, targ, spec);
    colfft_profile<<<NIMG * WH, 128, 0, stream>>>(spec, gsum);
    normalize_kernel<<<NIMG, 256, 0, stream>>>(gsum, prof);
    mse_kernel<<<1, 256, 0, stream>>>(prof, out);
}

// Round 3
// 87.313 us; speedup vs baseline: 2.1190x; 1.1493x over previous
//
#include <hip/hip_runtime.h>

#define H    256
#define W    256
#define WH   129            // W/2 + 1
#define VLEN 182            // max radial bin + 1
#define NIMG 64             // 32 pred + 32 target

__device__ __forceinline__ int bitrev8(int x) {
    return (int)(__brev((unsigned)x) >> 24);
}

__device__ __forceinline__ int isqrt_exact(int s2) {
    int r = (int)sqrtf((float)s2);
    while ((r + 1) * (r + 1) <= s2) ++r;
    while (r * r > s2) --r;
    return r;
}

// 256-point complex FFT in shared memory, DIT radix-2.
// 128 threads, sh[256] already loaded in bit-reversed order, twid[m] = e^{-2*pi*i*m/256}.
__device__ __forceinline__ void fft256(float2* sh, const float2* twid, int t) {
    #pragma unroll
    for (int lg = 1; lg <= 8; ++lg) {
        const int half = 1 << (lg - 1);
        const int pos  = t & (half - 1);
        const int i0   = ((t >> (lg - 1)) << lg) + pos;
        const int i1   = i0 + half;
        const float2 w = twid[pos << (8 - lg)];
        const float2 u = sh[i0];
        const float2 v = sh[i1];
        const float2 tv = make_float2(v.x * w.x - v.y * w.y,
                                      v.x * w.y + v.y * w.x);
        sh[i0] = make_float2(u.x + tv.x, u.y + tv.y);
        sh[i1] = make_float2(u.x - tv.x, u.y - tv.y);
        __syncthreads();
    }
}

__device__ __forceinline__ void init_twiddles(float2* twid, int t) {
    float s, c;
    __sincosf(-6.283185307179586f * (float)t * (1.0f / 256.0f), &s, &c);
    twid[t] = make_float2(c, s);
}

// One block of 128 threads per PAIR of image rows: luma + packed real FFT
// (two real rows as one complex FFT), unpack to two one-sided spectra.
// Also: block with pair==0 zeroes gsum for its image; block 0 computes the
// static radial-bin counts.
__global__ __launch_bounds__(128)
void gray_rowfft2(const float* __restrict__ pred, const float* __restrict__ targ,
                  float2* __restrict__ spec /* [NIMG][H][WH] */,
                  float* __restrict__ gsum /* [NIMG][VLEN] */,
                  int* __restrict__ counts /* [VLEN] */) {
    __shared__ float2 sh[256];
    __shared__ float2 twid[128];
    __shared__ int    scnt[VLEN];
    const int t    = threadIdx.x;
    const int b    = blockIdx.x;       // 0 .. NIMG*128-1
    const int img  = b >> 7;
    const int pair = b & 127;
    const int i0   = pair * 2;
    const float* src  = (img < 32) ? pred : targ;
    const float* base = src + (size_t)(img & 31) * (3 * H * W) + (size_t)i0 * W;

    init_twiddles(twid, t);

    if (pair == 0) {
        for (int v = t; v < VLEN; v += 128) gsum[img * VLEN + v] = 0.0f;
    }
    if (b == 0) {
        for (int v = t; v < VLEN; v += 128) scnt[v] = 0;
        __syncthreads();
        for (int e = t; e < H * WH; e += 128) {
            const int k  = e / WH;
            const int j  = e - k * WH;
            const int di = (k < 128) ? k : k - 256;
            atomicAdd(&scnt[isqrt_exact(di * di + j * j)], 1);
        }
        __syncthreads();
        for (int v = t; v < VLEN; v += 128) counts[v] = scnt[v];
    }

    for (int n = t; n < 256; n += 128) {
        const float ga = 0.299f * base[n]
                       + 0.587f * base[H * W + n]
                       + 0.114f * base[2 * H * W + n];
        const float gb = 0.299f * base[W + n]
                       + 0.587f * base[H * W + W + n]
                       + 0.114f * base[2 * H * W + W + n];
        sh[bitrev8(n)] = make_float2(ga, gb);
    }
    __syncthreads();

    fft256(sh, twid, t);

    // Unpack: Fa[k] = (Z[k]+conj(Z[-k]))/2, Fb[k] = -i(Z[k]-conj(Z[-k]))/2
    float2* da = spec + (size_t)img * (H * WH) + (size_t)i0 * WH;
    float2* db = da + WH;
    for (int k = t; k < WH; k += 128) {
        const float2 P = sh[k];
        const float2 Q = sh[(256 - k) & 255];
        da[k] = make_float2(0.5f * (P.x + Q.x), 0.5f * (P.y - Q.y));
        db[k] = make_float2(0.5f * (P.y + Q.y), 0.5f * (Q.x - P.x));
    }
}

// One block of 128 threads per (image, column): complex FFT along H, fused
// log-power + radial binning. Flushes per-block LDS bins to global sums.
__global__ __launch_bounds__(128)
void colfft_profile(const float2* __restrict__ spec,
                    float* __restrict__ gsum /* [NIMG][VLEN] */) {
    __shared__ float2 sh[256];
    __shared__ float2 twid[128];
    __shared__ float bins[VLEN];
    const int t   = threadIdx.x;
    const int idx = blockIdx.x;        // 0 .. NIMG*WH-1
    const int img = idx / WH;
    const int j   = idx - img * WH;
    const float2* base = spec + (size_t)img * (H * WH) + j;

    init_twiddles(twid, t);
    for (int v = t; v < VLEN; v += 128) bins[v] = 0.0f;
    for (int n = t; n < 256; n += 128)
        sh[bitrev8(n)] = base[(size_t)n * WH];
    __syncthreads();

    fft256(sh, twid, t);

    const int j2 = j * j;
    for (int n = t; n < 256; n += 128) {
        const int di = (n < 128) ? n : n - 256;
        const int r  = isqrt_exact(di * di + j2);
        const float2 F = sh[n];
        const float mag = 20.0f * logf(F.x * F.x + F.y * F.y + 1e-8f);
        atomicAdd(&bins[r], mag);
    }
    __syncthreads();

    // only bins in [j, floor(sqrt(128^2+j^2))] are touched by this column
    const int rmax = isqrt_exact(128 * 128 + j2);
    float* gs = gsum + (size_t)img * VLEN;
    for (int v = j + t; v <= rmax; v += 128)
        atomicAdd(&gs[v], bins[v]);
}

// 32 blocks (one per pred/target pair): per-bin mean, min/max normalize both
// profiles, partial sum of squared diffs.
__global__ __launch_bounds__(256)
void finish_kernel(const float* __restrict__ gsum, const int* __restrict__ counts,
                   float* __restrict__ partial) {
    __shared__ float pa[VLEN], pb[VLEN];
    __shared__ float2 red[256];
    const int t = threadIdx.x;
    const int b = blockIdx.x;          // 0..31

    if (t < VLEN) {
        const float c = (float)counts[t];
        pa[t] = gsum[(size_t)b * VLEN + t] / c;
        pb[t] = gsum[(size_t)(b + 32) * VLEN + t] / c;
    }
    __syncthreads();

    float va = (t < VLEN) ? pa[t] : 3.4e38f;
    float vb = (t < VLEN) ? pb[t] : 3.4e38f;
    red[t] = make_float2(va, vb); __syncthreads();
    for (int off = 128; off > 0; off >>= 1) {
        if (t < off) {
            red[t].x = fminf(red[t].x, red[t + off].x);
            red[t].y = fminf(red[t].y, red[t + off].y);
        }
        __syncthreads();
    }
    const float mna = red[0].x, mnb = red[0].y;
    __syncthreads();

    va = (t < VLEN) ? pa[t] - mna : -3.4e38f;
    vb = (t < VLEN) ? pb[t] - mnb : -3.4e38f;
    red[t] = make_float2(va, vb); __syncthreads();
    for (int off = 128; off > 0; off >>= 1) {
        if (t < off) {
            red[t].x = fmaxf(red[t].x, red[t + off].x);
            red[t].y = fmaxf(red[t].y, red[t + off].y);
        }
        __syncthreads();
    }
    const float mxa = red[0].x, mxb = red[0].y;
    __syncthreads();

    float d = 0.0f;
    if (t < VLEN)
        d = (pa[t] - mna) / mxa - (pb[t] - mnb) / mxb;
    red[t].x = d * d; __syncthreads();
    for (int off = 128; off > 0; off >>= 1) {
        if (t < off) red[t].x += red[t + off].x;
        __syncthreads();
    }
    if (t == 0) partial[b] = red[0].x;
}

// Single tiny block: final sum over 32 partials.
__global__ __launch_bounds__(64)
void final_kernel(const float* __restrict__ partial, float* __restrict__ out) {
    __shared__ float red[64];
    const int t = threadIdx.x;
    red[t] = (t < 32) ? partial[t] : 0.0f;
    __syncthreads();
    for (int off = 32; off > 0; off >>= 1) {
        if (t < off) red[t] += red[t + off];
        __syncthreads();
    }
    if (t == 0) out[0] = red[0] / (float)(32 * VLEN);
}

extern "C" void kernel_launch(void* const* d_in, const int* in_sizes, int n_in,
                              void* d_out, int out_size, void* d_ws, size_t ws_size,
                              hipStream_t stream) {
    const float* pred = (const float*)d_in[0];
    const float* targ = (const float*)d_in[1];
    float* out = (float*)d_out;

    char* ws = (char*)d_ws;
    float2* spec = (float2*)ws;                                  // NIMG*H*WH complex
    ws += (size_t)NIMG * H * WH * sizeof(float2);
    float* gsum = (float*)ws;                                    // NIMG*VLEN floats
    ws += (size_t)NIMG * VLEN * sizeof(float);
    int* counts = (int*)ws;                                      // VLEN ints
    ws += (size_t)VLEN * sizeof(int);
    float* partial = (float*)ws;                                 // 32 floats

    gray_rowfft2<<<NIMG * 128, 128, 0, stream>>>(pred, targ, spec, gsum, counts);
    colfft_profile<<<NIMG * WH, 128, 0, stream>>>(spec, gsum);
    finish_kernel<<<32, 256, 0, stream>>>(gsum, counts, partial);
    final_kernel<<<1, 64, 0, stream>>>(partial, out);
}

// Round 4
// 51.699 us; speedup vs baseline: 3.5787x; 1.6889x over previous
//
#include <hip/hip_runtime.h>
#include <hip/hip_fp16.h>

#define H    256
#define W    256
#define WH   129            // W/2 + 1
#define VLEN 182            // max radial bin + 1
#define NIMG 64             // 32 pred + 32 target
#define TWO_PI 6.283185307179586f
#define TSTRIDE 35          // LDS tile row stride (half2 units) for colfft_bin

__device__ __forceinline__ int isqrt_exact(int s2) {
    int r = (int)sqrtf((float)s2);
    while ((r + 1) * (r + 1) <= s2) ++r;
    while (r * r > s2) --r;
    return r;
}

__device__ __forceinline__ float2 cmul(float2 a, float2 b) {
    return make_float2(a.x * b.x - a.y * b.y, a.x * b.y + a.y * b.x);
}

// 256-point DIF FFT held by one 64-lane wave; thread t owns positions
// i = t + 64r (r=0..3). On exit, position i holds X[bitrev8(i)].
// All twiddles depend only on t (and stage), never on r.
__device__ __forceinline__ void wfft256(float2 z[4], int t) {
    float s, c;
    // m=256: reg pairs (0,2) and (1,3); w = e^{-2pi i t/256}, pair(1,3) gets w*(-i)
    __sincosf(-TWO_PI * (1.0f / 256.0f) * (float)t, &s, &c);
    {
        const float2 w0 = make_float2(c, s);
        const float2 w1 = make_float2(s, -c);          // w0 * (-i)
        float2 u0 = z[0], v0 = z[2], u1 = z[1], v1 = z[3];
        z[0] = make_float2(u0.x + v0.x, u0.y + v0.y);
        z[2] = cmul(make_float2(u0.x - v0.x, u0.y - v0.y), w0);
        z[1] = make_float2(u1.x + v1.x, u1.y + v1.y);
        z[3] = cmul(make_float2(u1.x - v1.x, u1.y - v1.y), w1);
    }
    // m=128: reg pairs (0,1) and (2,3); w = e^{-2pi i t/128}
    __sincosf(-TWO_PI * (1.0f / 128.0f) * (float)t, &s, &c);
    {
        const float2 w = make_float2(c, s);
        float2 u0 = z[0], v0 = z[1], u1 = z[2], v1 = z[3];
        z[0] = make_float2(u0.x + v0.x, u0.y + v0.y);
        z[1] = cmul(make_float2(u0.x - v0.x, u0.y - v0.y), w);
        z[2] = make_float2(u1.x + v1.x, u1.y + v1.y);
        z[3] = cmul(make_float2(u1.x - v1.x, u1.y - v1.y), w);
    }
    // m=64,32,16,8: lane-xor m/2, w = e^{-2pi i (t&(m/2-1))/m}, same for all regs
    #pragma unroll
    for (int m = 64; m >= 8; m >>= 1) {
        const int hm = m >> 1;
        __sincosf((-TWO_PI / (float)m) * (float)(t & (hm - 1)), &s, &c);
        const float2 w = make_float2(c, s);
        const bool hi = (t & hm) != 0;
        #pragma unroll
        for (int r = 0; r < 4; ++r) {
            float2 o;
            o.x = __shfl_xor(z[r].x, hm, 64);
            o.y = __shfl_xor(z[r].y, hm, 64);
            if (hi) z[r] = cmul(make_float2(o.x - z[r].x, o.y - z[r].y), w);
            else    z[r] = make_float2(z[r].x + o.x, z[r].y + o.y);
        }
    }
    // m=4: lane-xor 2; w = 1 (t even) or -i (t odd)
    {
        const bool hi  = (t & 2) != 0;
        const bool odd = (t & 1) != 0;
        #pragma unroll
        for (int r = 0; r < 4; ++r) {
            float2 o;
            o.x = __shfl_xor(z[r].x, 2, 64);
            o.y = __shfl_xor(z[r].y, 2, 64);
            float2 d = hi ? make_float2(o.x - z[r].x, o.y - z[r].y)
                          : make_float2(z[r].x + o.x, z[r].y + o.y);
            if (hi && odd) d = make_float2(d.y, -d.x);   // * (-i)
            z[r] = d;
        }
    }
    // m=2: lane-xor 1; w = 1
    {
        const bool hi = (t & 1) != 0;
        #pragma unroll
        for (int r = 0; r < 4; ++r) {
            float2 o;
            o.x = __shfl_xor(z[r].x, 1, 64);
            o.y = __shfl_xor(z[r].y, 1, 64);
            z[r] = hi ? make_float2(o.x - z[r].x, o.y - z[r].y)
                      : make_float2(z[r].x + o.x, z[r].y + o.y);
        }
    }
}

// Blocks of 4 waves; each wave: luma for a packed row-pair, wave FFT, LDS
// unpack of the two real spectra, fp16 store. Blocks with (b&31)==0 zero gsum.
__global__ __launch_bounds__(256)
void rowfft_wave(const float* __restrict__ pred, const float* __restrict__ targ,
                 __half2* __restrict__ G /* [NIMG][256][WH] */,
                 float* __restrict__ gsum /* [NIMG][VLEN] */) {
    __shared__ float zbuf[4][512];     // per wave: re[256] + im[256], sigma-swizzled
    const int tid  = threadIdx.x;
    const int t    = tid & 63;
    const int wid  = tid >> 6;
    const int b    = blockIdx.x;       // 0..2047
    const int img  = b >> 5;           // 32 blocks per image
    const int pair = ((b & 31) << 2) | wid;
    const int rowA = pair * 2;

    if ((b & 31) == 0) {
        for (int v = tid; v < VLEN; v += 256) gsum[img * VLEN + v] = 0.0f;
    }

    const float* src  = (img < 32) ? pred : targ;
    const float* base = src + (size_t)(img & 31) * (3 * H * W) + (size_t)rowA * W;

    float2 z[4];
    #pragma unroll
    for (int r = 0; r < 4; ++r) {
        const int n = t + (r << 6);
        const float ga = 0.299f * base[n]
                       + 0.587f * base[H * W + n]
                       + 0.114f * base[2 * H * W + n];
        const float gb = 0.299f * base[W + n]
                       + 0.587f * base[H * W + W + n]
                       + 0.114f * base[2 * H * W + W + n];
        z[r] = make_float2(ga, gb);
    }

    wfft256(z, t);

    float* zr = zbuf[wid];
    float* zi = zr + 256;
    #pragma unroll
    for (int r = 0; r < 4; ++r) {
        const int x  = (int)(__brev((unsigned)(t + (r << 6))) >> 24);
        const int sx = x ^ (x >> 5);
        zr[sx] = z[r].x; zi[sx] = z[r].y;
    }
    __syncthreads();

    // Unpack: Ga[k] = (Z[k]+conj(Z[-k]))/2, Gb[k] = -i(Z[k]-conj(Z[-k]))/2
    __half2* da = G + ((size_t)img * 256 + rowA) * WH;
    __half2* db = da + WH;
    for (int k = t; k <= 128; k += 64) {
        const int kq = (256 - k) & 255;
        const int sk = k ^ (k >> 5), sq = kq ^ (kq >> 5);
        const float2 P = make_float2(zr[sk], zi[sk]);
        const float2 Q = make_float2(zr[sq], zi[sq]);
        da[k] = __floats2half2_rn(0.5f * (P.x + Q.x), 0.5f * (P.y - Q.y));
        db[k] = __floats2half2_rn(0.5f * (P.y + Q.y), 0.5f * (Q.x - P.x));
    }
}

// 4 blocks per image (33/33/33/30 columns). Stage fp16 tile in LDS, wave-FFT
// each column, fused log-power + radial binning, one atomic flush per block.
__global__ __launch_bounds__(1024)
void colfft_bin(const __half2* __restrict__ G, float* __restrict__ gsum) {
    __shared__ __half2 tile[256 * TSTRIDE];
    __shared__ float bins[VLEN];
    const int tid = threadIdx.x;
    const int t   = tid & 63;
    const int wid = tid >> 6;          // 0..15
    const int blk = blockIdx.x;        // 0..255
    const int img = blk >> 2;
    const int q   = blk & 3;
    const int j0  = q * 33;
    const int nc  = (q < 3) ? 33 : 30;

    for (int v = tid; v < VLEN; v += 1024) bins[v] = 0.0f;

    const __half2* g = G + (size_t)img * 256 * WH;
    for (int e = tid; e < 256 * 33; e += 1024) {
        const int row = e / 33;
        const int cl  = e - row * 33;
        if (j0 + cl < WH)
            tile[row * TSTRIDE + cl] = g[row * WH + j0 + cl];
    }
    __syncthreads();

    for (int cl = wid; cl < nc; cl += 16) {
        const int j = j0 + cl;
        float2 z[4];
        #pragma unroll
        for (int r = 0; r < 4; ++r)
            z[r] = __half22float2(tile[(t + (r << 6)) * TSTRIDE + cl]);

        wfft256(z, t);

        const int j2 = j * j;
        #pragma unroll
        for (int r = 0; r < 4; ++r) {
            const int n   = (int)(__brev((unsigned)(t + (r << 6))) >> 24);
            const int di  = (n < 128) ? n : n - 256;
            const int rad = isqrt_exact(di * di + j2);
            const float p = z[r].x * z[r].x + z[r].y * z[r].y + 1e-8f;
            atomicAdd(&bins[rad], 20.0f * __logf(p));
        }
    }
    __syncthreads();

    const int jmax = j0 + nc - 1;
    const int rmax = isqrt_exact(128 * 128 + jmax * jmax);
    float* gs = gsum + (size_t)img * VLEN;
    for (int v = j0 + tid; v <= rmax; v += 1024)
        atomicAdd(&gs[v], bins[v]);
}

// One block: static bin counts, per-pair min/max normalize, MSE -> out.
__global__ __launch_bounds__(1024)
void finish1(const float* __restrict__ gsum, float* __restrict__ out) {
    __shared__ int   scnt[VLEN];
    __shared__ float facc[16];
    const int tid = threadIdx.x;
    const int t   = tid & 63;
    const int wid = tid >> 6;

    for (int v = tid; v < VLEN; v += 1024) scnt[v] = 0;
    __syncthreads();
    for (int e = tid; e < H * WH; e += 1024) {
        const int k  = e / WH;
        const int j  = e - k * WH;
        const int di = (k < 128) ? k : k - 256;
        atomicAdd(&scnt[isqrt_exact(di * di + j * j)], 1);
    }
    __syncthreads();

    float total = 0.0f;
    for (int pr = wid; pr < 32; pr += 16) {
        float a[3], b[3];
        float mna = 1e30f, mnb = 1e30f, mxa = -1e30f, mxb = -1e30f;
        #pragma unroll
        for (int r = 0; r < 3; ++r) {
            const int v = t + (r << 6);
            if (v < VLEN) {
                const float ic = 1.0f / (float)scnt[v];
                a[r] = gsum[(size_t)pr * VLEN + v] * ic;
                b[r] = gsum[(size_t)(pr + 32) * VLEN + v] * ic;
                mna = fminf(mna, a[r]); mxa = fmaxf(mxa, a[r]);
                mnb = fminf(mnb, b[r]); mxb = fmaxf(mxb, b[r]);
            } else { a[r] = 0.0f; b[r] = 0.0f; }
        }
        #pragma unroll
        for (int m = 32; m >= 1; m >>= 1) {
            mna = fminf(mna, __shfl_xor(mna, m, 64));
            mxa = fmaxf(mxa, __shfl_xor(mxa, m, 64));
            mnb = fminf(mnb, __shfl_xor(mnb, m, 64));
            mxb = fmaxf(mxb, __shfl_xor(mxb, m, 64));
        }
        const float inva = 1.0f / (mxa - mna);
        const float invb = 1.0f / (mxb - mnb);
        float sacc = 0.0f;
        #pragma unroll
        for (int r = 0; r < 3; ++r) {
            const int v = t + (r << 6);
            if (v < VLEN) {
                const float d = (a[r] - mna) * inva - (b[r] - mnb) * invb;
                sacc += d * d;
            }
        }
        #pragma unroll
        for (int m = 32; m >= 1; m >>= 1) sacc += __shfl_xor(sacc, m, 64);
        total += sacc;
    }
    if (t == 0) facc[wid] = total;
    __syncthreads();
    if (tid == 0) {
        float r = 0.0f;
        for (int i = 0; i < 16; ++i) r += facc[i];
        out[0] = r / (float)(32 * VLEN);
    }
}

extern "C" void kernel_launch(void* const* d_in, const int* in_sizes, int n_in,
                              void* d_out, int out_size, void* d_ws, size_t ws_size,
                              hipStream_t stream) {
    const float* pred = (const float*)d_in[0];
    const float* targ = (const float*)d_in[1];
    float* out = (float*)d_out;

    char* ws = (char*)d_ws;
    __half2* G = (__half2*)ws;                                   // NIMG*256*WH half2
    ws += (size_t)NIMG * 256 * WH * sizeof(__half2);
    float* gsum = (float*)ws;                                    // NIMG*VLEN floats

    rowfft_wave<<<NIMG * 32, 256, 0, stream>>>(pred, targ, G, gsum);
    colfft_bin<<<NIMG * 4, 1024, 0, stream>>>(G, gsum);
    finish1<<<1, 1024, 0, stream>>>(gsum, out);
}